// Round 9
// baseline (150.652 us; speedup 1.0000x reference)
//
#include <hip/hip_runtime.h>
#include <hip/hip_bf16.h>

#define TGT 256
#define BSZ 8
#define E   256
#define SRC 4096

typedef __attribute__((ext_vector_type(8))) short           bf16x8;
typedef __attribute__((ext_vector_type(4))) float           f32x4;
typedef __attribute__((ext_vector_type(4))) float           f4;
typedef __attribute__((ext_vector_type(8))) unsigned short  u16x8;
typedef __attribute__((ext_vector_type(4))) unsigned short  u16x4;

__device__ inline unsigned short f2b(float x) {
    union { __hip_bfloat16 h; unsigned short u; } cv;
    cv.h = __float2bfloat16(x);
    return cv.u;
}

__device__ inline float b2f(unsigned short u) {
    union { float f; unsigned v; } c;
    c.v = ((unsigned)u) << 16;
    return c.f;
}

__device__ inline bf16x8 cvt8v(const float* __restrict__ p) {
    f4 lo = *(const f4*)p;
    f4 hi = *(const f4*)(p + 4);
    bf16x8 r;
    #pragma unroll
    for (int j = 0; j < 4; ++j) { r[j] = (short)f2b(lo[j]); r[4 + j] = (short)f2b(hi[j]); }
    return r;
}

// ---------------------------------------------------------------------------
// prep: grid (64, 9).  [R0 verbatim — measured ~10 us ≈ its traffic roofline]
//  by<8 : v_frag — value(SRC,BSZ,E) fp32 -> vtf in B-fragment order (bf16)
//  by==8: w_frag — W(E,E) fp32 -> wf in B-fragment order (bf16)
// ---------------------------------------------------------------------------
__global__ __launch_bounds__(256) void prep(
    const float* __restrict__ value, const float* __restrict__ wgt,
    unsigned short* __restrict__ vtf, unsigned short* __restrict__ wf)
{
    const int tid = threadIdx.x;

    if (blockIdx.y == 8) {               // ---- W frag pass (64 tiny blocks)
        if (tid < 128) {
            int o    = blockIdx.x * 128 + tid;   // 0..8191
            int et   = o >> 9;
            int ks   = (o >> 6) & 7;
            int lane = o & 63;
            int quad = lane >> 4, l15 = lane & 15;
            bf16x8 v = cvt8v(wgt + (size_t)(et * 16 + l15) * E + ks * 32 + quad * 8);
            *(bf16x8*)&wf[(size_t)o * 8] = v;
        }
        return;
    }

    __shared__ unsigned short tile[64 * 264];   // pitch 264 u16
    const int kch = blockIdx.x;                 // 0..63
    const int b   = blockIdx.y;
    const int k0  = kch * 64;

    #pragma unroll
    for (int i = 0; i < 16; ++i) {
        int lin = i * 256 + tid;                // 0..4095
        int row = lin >> 6;                     // k-local 0..63
        int c4  = lin & 63;                     // e float4 idx
        f4 v = *(const f4*)(value + (size_t)(k0 + row) * (BSZ * E)
                                  + (size_t)b * E + c4 * 4);
        #pragma unroll
        for (int j = 0; j < 4; ++j) tile[row * 264 + c4 * 4 + j] = f2b(v[j]);
    }
    __syncthreads();

    #pragma unroll
    for (int i = 0; i < 8; ++i) {
        int o    = i * 256 + tid;               // 0..2047 octets
        int et   = o >> 7;
        int ksl  = (o >> 6) & 1;
        int lane = o & 63;
        int quad = lane >> 4, l15 = lane & 15;
        u16x8 pk;
        #pragma unroll
        for (int j = 0; j < 8; ++j)
            pk[j] = tile[(ksl * 32 + quad * 8 + j) * 264 + et * 16 + l15];
        size_t ks = (size_t)kch * 2 + ksl;
        *(u16x8*)&vtf[((((size_t)b * 16 + et) * 128 + ks) * 64 + lane) * 8] = pk;
    }
}

// ---------------------------------------------------------------------------
// gemm1: part[kc] = M_b[t-tile, kc-chunk] @ V_b[kc-chunk] + fused out1 copy.
// R8 structure (prologue load burst, 4-stage, 512x512) with two changes:
//  - mask loads + out1 stores are NONTEMPORAL (clean test this time: tile
//    shape unchanged). Theory: the 67 MB read-once/write-once streams evict
//    each XCD L2's vtf slice (re-read 8x, 134 MB) and the part slices gemm2
//    reads back. NT keeps reuse data L2-resident.
//  - part stored in BF16 (halves part W here + R in gemm2; same rounding
//    point R1 used and passed). part stores stay REGULAR (L2-allocating).
// ---------------------------------------------------------------------------
#define AP 136   // A pitch u16: 272 B rows (16B-aligned)

__global__ __launch_bounds__(512) void gemm1(
    const float* __restrict__ mask,
    const unsigned short* __restrict__ vtf,
    float* __restrict__ out1,
    unsigned short* __restrict__ part)
{
    __shared__ unsigned short As[2][32 * AP];   // 2 x 8.7 KB
    const int bx  = blockIdx.x;
    const int b   = bx & 7;                     // XCD swizzle
    const int tt  = (bx >> 3) & 7;
    const int kc  = bx >> 6;                    // 0..7, K-chunk 512
    const int t0  = tt * 32;
    const int k0  = kc * 512;
    const int tid = threadIdx.x;
    const int w    = tid >> 6;
    const int lane = tid & 63;
    const int quad = lane >> 4;
    const int l15  = lane & 15;

    const float* mbase = mask + (size_t)b * TGT * SRC + (size_t)t0 * SRC + k0;
    float*       obase = out1 + (size_t)b * TGT * SRC + (size_t)t0 * SRC + k0;
    const int sr0 = tid >> 5, sr1 = sr0 + 16, sc = (tid & 31) * 4;

    // wave w owns e columns [w*32, w*32+32): et pair (2w, 2w+1)
    const unsigned short* bfr0 = vtf + (((size_t)b * 16 + 2 * w) * 128 + (size_t)kc * 16) * 512;
    const unsigned short* bfr1 = bfr0 + (size_t)128 * 512;

    // ---- prologue: ONE burst of all 8 mask loads (NT: read-once stream)
    f4 mv[8];
    #pragma unroll
    for (int s = 0; s < 4; ++s) {
        mv[2 * s]     = __builtin_nontemporal_load(
                            (const f4*)(mbase + (size_t)sr0 * SRC + s * 128 + sc));
        mv[2 * s + 1] = __builtin_nontemporal_load(
                            (const f4*)(mbase + (size_t)sr1 * SRC + s * 128 + sc));
    }

    // stage 0: out1 copy (NT) + cvt into As[0]
    {
        __builtin_nontemporal_store(mv[0], (f4*)(obase + (size_t)sr0 * SRC + sc));
        __builtin_nontemporal_store(mv[1], (f4*)(obase + (size_t)sr1 * SRC + sc));
        u16x4 p0, p1;
        #pragma unroll
        for (int j = 0; j < 4; ++j) { p0[j] = f2b(mv[0][j]); p1[j] = f2b(mv[1][j]); }
        *(u16x4*)&As[0][sr0 * AP + sc] = p0;
        *(u16x4*)&As[0][sr1 * AP + sc] = p1;
    }
    __syncthreads();

    f32x4 acc00 = {}, acc01 = {}, acc10 = {}, acc11 = {};

    #pragma unroll
    for (int s = 0; s < 4; ++s) {               // 4 stages x 128 k
        #pragma unroll
        for (int q = 0; q < 4; ++q) {
            bf16x8 B0 = *(const bf16x8*)(bfr0 + ((size_t)(s * 4 + q) * 64 + lane) * 8);
            bf16x8 B1 = *(const bf16x8*)(bfr1 + ((size_t)(s * 4 + q) * 64 + lane) * 8);
            bf16x8 a0 = *(const bf16x8*)&As[s & 1][ l15       * AP + q * 32 + quad * 8];
            bf16x8 a1 = *(const bf16x8*)&As[s & 1][(l15 + 16) * AP + q * 32 + quad * 8];
            acc00 = __builtin_amdgcn_mfma_f32_16x16x32_bf16(a0, B0, acc00, 0, 0, 0);
            acc01 = __builtin_amdgcn_mfma_f32_16x16x32_bf16(a0, B1, acc01, 0, 0, 0);
            acc10 = __builtin_amdgcn_mfma_f32_16x16x32_bf16(a1, B0, acc10, 0, 0, 0);
            acc11 = __builtin_amdgcn_mfma_f32_16x16x32_bf16(a1, B1, acc11, 0, 0, 0);
        }
        if (s < 3) {
            __builtin_nontemporal_store(
                mv[2 * s + 2], (f4*)(obase + (size_t)sr0 * SRC + (s + 1) * 128 + sc));
            __builtin_nontemporal_store(
                mv[2 * s + 3], (f4*)(obase + (size_t)sr1 * SRC + (s + 1) * 128 + sc));
            u16x4 p0, p1;
            #pragma unroll
            for (int j = 0; j < 4; ++j) {
                p0[j] = f2b(mv[2 * s + 2][j]);
                p1[j] = f2b(mv[2 * s + 3][j]);
            }
            *(u16x4*)&As[(s + 1) & 1][sr0 * AP + sc] = p0;
            *(u16x4*)&As[(s + 1) & 1][sr1 * AP + sc] = p1;
        }
        __syncthreads();
    }

    // epilogue: wave-private 32x32 partial -> BF16 part (regular stores)
    // D layout: col = lane&15 (n), row = quad*4 + reg (m)  [verified m89/m91]
    unsigned short* pb = part + ((size_t)kc * BSZ + b) * TGT * E;
    #pragma unroll
    for (int r = 0; r < 4; ++r) {
        int rr0 = t0 + quad * 4 + r;
        int rr1 = rr0 + 16;
        int c0  = w * 32 + l15;
        pb[(size_t)rr0 * E + c0]      = f2b(acc00[r]);
        pb[(size_t)rr0 * E + c0 + 16] = f2b(acc01[r]);
        pb[(size_t)rr1 * E + c0]      = f2b(acc10[r]);
        pb[(size_t)rr1 * E + c0 + 16] = f2b(acc11[r]);
    }
}

// ---------------------------------------------------------------------------
// gemm2_fused: out0[t,b,:] = (sum_kc part[kc])[b,t,:] @ W^T + bias.
// part now BF16 (half the read bytes; b-slice ~1 MB may be L2-hot on XCD b).
// ---------------------------------------------------------------------------
#define PSTRIDE ((size_t)BSZ * TGT * E)

__global__ __launch_bounds__(256) void gemm2_fused(
    const unsigned short* __restrict__ part,
    const unsigned short* __restrict__ wf,
    const float* __restrict__ bias,
    float* __restrict__ out0)
{
    __shared__ unsigned short ct[16 * 264];     // 16 t-rows x 256 e, pitch 264
    const int blk  = blockIdx.x;                // 0..127
    const int b    = blk & 7;
    const int tt16 = blk >> 3;                  // 0..15
    const int tid  = threadIdx.x;

    // ---- reduce 8 bf16 K-partials in fp32 -> bf16 LDS tile
    const unsigned short* pb = part + (size_t)b * TGT * E + (size_t)(tt16 * 16) * E;
    #pragma unroll
    for (int i = 0; i < 4; ++i) {
        int idx = i * 256 + tid;                // 0..1023
        int row = idx >> 6;                     // 0..15
        int c4  = idx & 63;
        const unsigned short* ap = pb + (size_t)row * E + c4 * 4;
        f4 s = {};
        #pragma unroll
        for (int p = 0; p < 8; ++p) {
            u16x4 v = *(const u16x4*)(ap + p * PSTRIDE);
            #pragma unroll
            for (int j = 0; j < 4; ++j) s[j] += b2f(v[j]);
        }
        #pragma unroll
        for (int j = 0; j < 4; ++j) ct[row * 264 + c4 * 4 + j] = f2b(s[j]);
    }
    __syncthreads();

    // ---- MFMA: 4 waves x 4 et tiles each
    const int w    = tid >> 6;
    const int lane = tid & 63;
    const int quad = lane >> 4;
    const int l15  = lane & 15;

    bf16x8 A[8];
    #pragma unroll
    for (int ks = 0; ks < 8; ++ks)
        A[ks] = *(const bf16x8*)&ct[l15 * 264 + ks * 32 + quad * 8];

    #pragma unroll
    for (int e4 = 0; e4 < 4; ++e4) {
        int et = w * 4 + e4;
        const unsigned short* bf = wf + ((size_t)et * 8 * 64 + lane) * 8;
        f32x4 acc = {};
        #pragma unroll
        for (int ks = 0; ks < 8; ++ks) {
            bf16x8 bb = *(const bf16x8*)(bf + (size_t)ks * 512);
            acc = __builtin_amdgcn_mfma_f32_16x16x32_bf16(A[ks], bb, acc, 0, 0, 0);
        }
        const float bval = bias[et * 16 + l15];
        #pragma unroll
        for (int r = 0; r < 4; ++r) {
            int t = tt16 * 16 + quad * 4 + r;
            int e = et * 16 + l15;
            out0[(size_t)t * (BSZ * E) + (size_t)b * E + e] = acc[r] + bval;
        }
    }
}

// ---------------------------------------------------------------------------
extern "C" void kernel_launch(void* const* d_in, const int* in_sizes, int n_in,
                              void* d_out, int out_size, void* d_ws, size_t ws_size,
                              hipStream_t stream)
{
    // inputs: 0=query(unused) 1=key(unused) 2=value 3=proposal_mask 4=W 5=bias
    const float* value = (const float*)d_in[2];
    const float* mask  = (const float*)d_in[3];
    const float* wgt   = (const float*)d_in[4];
    const float* bias  = (const float*)d_in[5];

    float* out0 = (float*)d_out;                              // (256,8,256)
    float* out1 = (float*)d_out + (size_t)TGT * BSZ * E;      // (8,256,4096)

    // ws layout: vtf bf16 16.8MB | wf bf16 128KB | part bf16 [8][b][t][e] 8.4MB
    unsigned short* vtf  = (unsigned short*)d_ws;
    unsigned short* wf   = vtf + (size_t)BSZ * E * SRC;
    unsigned short* part = wf + (size_t)16 * 8 * 64 * 8;

    prep<<<dim3(64, 9), 256, 0, stream>>>(value, wgt, vtf, wf);
    gemm1<<<512, 512, 0, stream>>>(mask, vtf, out1, part);
    gemm2_fused<<<128, 256, 0, stream>>>(part, wf, bias, out0);
}

// Round 10
// 145.669 us; speedup vs baseline: 1.0342x; 1.0342x over previous
//
#include <hip/hip_runtime.h>
#include <hip/hip_bf16.h>

#define TGT 256
#define BSZ 8
#define E   256
#define SRC 4096

typedef __attribute__((ext_vector_type(8))) short           bf16x8;
typedef __attribute__((ext_vector_type(4))) float           f32x4;
typedef __attribute__((ext_vector_type(4))) float           f4;
typedef __attribute__((ext_vector_type(8))) unsigned short  u16x8;
typedef __attribute__((ext_vector_type(4))) unsigned short  u16x4;

__device__ inline unsigned short f2b(float x) {
    union { __hip_bfloat16 h; unsigned short u; } cv;
    cv.h = __float2bfloat16(x);
    return cv.u;
}

__device__ inline float b2f(unsigned short u) {
    union { float f; unsigned v; } c;
    c.v = ((unsigned)u) << 16;
    return c.f;
}

__device__ inline bf16x8 cvt8v(const float* __restrict__ p) {
    f4 lo = *(const f4*)p;
    f4 hi = *(const f4*)(p + 4);
    bf16x8 r;
    #pragma unroll
    for (int j = 0; j < 4; ++j) { r[j] = (short)f2b(lo[j]); r[4 + j] = (short)f2b(hi[j]); }
    return r;
}

// ---------------------------------------------------------------------------
// prep: grid (64, 9).  [R0 verbatim — measured ~10 us ≈ its traffic roofline]
//  by<8 : v_frag — value(SRC,BSZ,E) fp32 -> vtf in B-fragment order (bf16)
//  by==8: w_frag — W(E,E) fp32 -> wf in B-fragment order (bf16)
// ---------------------------------------------------------------------------
__global__ __launch_bounds__(256) void prep(
    const float* __restrict__ value, const float* __restrict__ wgt,
    unsigned short* __restrict__ vtf, unsigned short* __restrict__ wf)
{
    const int tid = threadIdx.x;

    if (blockIdx.y == 8) {               // ---- W frag pass (64 tiny blocks)
        if (tid < 128) {
            int o    = blockIdx.x * 128 + tid;   // 0..8191
            int et   = o >> 9;
            int ks   = (o >> 6) & 7;
            int lane = o & 63;
            int quad = lane >> 4, l15 = lane & 15;
            bf16x8 v = cvt8v(wgt + (size_t)(et * 16 + l15) * E + ks * 32 + quad * 8);
            *(bf16x8*)&wf[(size_t)o * 8] = v;
        }
        return;
    }

    __shared__ unsigned short tile[64 * 264];   // pitch 264 u16
    const int kch = blockIdx.x;                 // 0..63
    const int b   = blockIdx.y;
    const int k0  = kch * 64;

    #pragma unroll
    for (int i = 0; i < 16; ++i) {
        int lin = i * 256 + tid;                // 0..4095
        int row = lin >> 6;                     // k-local 0..63
        int c4  = lin & 63;                     // e float4 idx
        f4 v = *(const f4*)(value + (size_t)(k0 + row) * (BSZ * E)
                                  + (size_t)b * E + c4 * 4);
        #pragma unroll
        for (int j = 0; j < 4; ++j) tile[row * 264 + c4 * 4 + j] = f2b(v[j]);
    }
    __syncthreads();

    #pragma unroll
    for (int i = 0; i < 8; ++i) {
        int o    = i * 256 + tid;               // 0..2047 octets
        int et   = o >> 7;
        int ksl  = (o >> 6) & 1;
        int lane = o & 63;
        int quad = lane >> 4, l15 = lane & 15;
        u16x8 pk;
        #pragma unroll
        for (int j = 0; j < 8; ++j)
            pk[j] = tile[(ksl * 32 + quad * 8 + j) * 264 + et * 16 + l15];
        size_t ks = (size_t)kch * 2 + ksl;
        *(u16x8*)&vtf[((((size_t)b * 16 + et) * 128 + ks) * 64 + lane) * 8] = pk;
    }
}

// ---------------------------------------------------------------------------
// gemm1: part[kc] = M_b[t-tile, kc-chunk] @ V_b[kc-chunk] + fused out1 copy.
// R8 structure (prologue mask-load burst, 4-stage dbuf, 512x512) with:
//  - NT removed (R9: NT cost ~4-5 us — partial-line HBM writes; refuted)
//  - ALL 8 out1 stores deferred to AFTER the MFMA loop: in R8 each of the 4
//    stage-barriers drained vmcnt(0) with 2 outstanding out1 stores/thread
//    (~200-400 cy write-ack), stalling all 16 waves/CU per stage. mv[] is
//    live in regs anyway; stores now drain async during epilogue/endpgm.
//  - last (s=3) barrier dropped (no LDS write follows it)
//  - part stored BF16 (halves part W here + R in gemm2; rounding passed R9)
// ---------------------------------------------------------------------------
#define AP 136   // A pitch u16: 272 B rows (16B-aligned)

__global__ __launch_bounds__(512) void gemm1(
    const float* __restrict__ mask,
    const unsigned short* __restrict__ vtf,
    float* __restrict__ out1,
    unsigned short* __restrict__ part)
{
    __shared__ unsigned short As[2][32 * AP];   // 2 x 8.7 KB
    const int bx  = blockIdx.x;
    const int b   = bx & 7;                     // XCD swizzle
    const int tt  = (bx >> 3) & 7;
    const int kc  = bx >> 6;                    // 0..7, K-chunk 512
    const int t0  = tt * 32;
    const int k0  = kc * 512;
    const int tid = threadIdx.x;
    const int w    = tid >> 6;
    const int lane = tid & 63;
    const int quad = lane >> 4;
    const int l15  = lane & 15;

    const float* mbase = mask + (size_t)b * TGT * SRC + (size_t)t0 * SRC + k0;
    float*       obase = out1 + (size_t)b * TGT * SRC + (size_t)t0 * SRC + k0;
    const int sr0 = tid >> 5, sr1 = sr0 + 16, sc = (tid & 31) * 4;

    // wave w owns e columns [w*32, w*32+32): et pair (2w, 2w+1)
    const unsigned short* bfr0 = vtf + (((size_t)b * 16 + 2 * w) * 128 + (size_t)kc * 16) * 512;
    const unsigned short* bfr1 = bfr0 + (size_t)128 * 512;

    // ---- prologue: ONE burst of all 8 mask loads
    f4 mv[8];
    #pragma unroll
    for (int s = 0; s < 4; ++s) {
        mv[2 * s]     = *(const f4*)(mbase + (size_t)sr0 * SRC + s * 128 + sc);
        mv[2 * s + 1] = *(const f4*)(mbase + (size_t)sr1 * SRC + s * 128 + sc);
    }

    // stage 0: cvt into As[0] (no stores here — deferred)
    {
        u16x4 p0, p1;
        #pragma unroll
        for (int j = 0; j < 4; ++j) { p0[j] = f2b(mv[0][j]); p1[j] = f2b(mv[1][j]); }
        *(u16x4*)&As[0][sr0 * AP + sc] = p0;
        *(u16x4*)&As[0][sr1 * AP + sc] = p1;
    }
    __syncthreads();

    f32x4 acc00 = {}, acc01 = {}, acc10 = {}, acc11 = {};

    #pragma unroll
    for (int s = 0; s < 4; ++s) {               // 4 stages x 128 k
        #pragma unroll
        for (int q = 0; q < 4; ++q) {
            bf16x8 B0 = *(const bf16x8*)(bfr0 + ((size_t)(s * 4 + q) * 64 + lane) * 8);
            bf16x8 B1 = *(const bf16x8*)(bfr1 + ((size_t)(s * 4 + q) * 64 + lane) * 8);
            bf16x8 a0 = *(const bf16x8*)&As[s & 1][ l15       * AP + q * 32 + quad * 8];
            bf16x8 a1 = *(const bf16x8*)&As[s & 1][(l15 + 16) * AP + q * 32 + quad * 8];
            acc00 = __builtin_amdgcn_mfma_f32_16x16x32_bf16(a0, B0, acc00, 0, 0, 0);
            acc01 = __builtin_amdgcn_mfma_f32_16x16x32_bf16(a0, B1, acc01, 0, 0, 0);
            acc10 = __builtin_amdgcn_mfma_f32_16x16x32_bf16(a1, B0, acc10, 0, 0, 0);
            acc11 = __builtin_amdgcn_mfma_f32_16x16x32_bf16(a1, B1, acc11, 0, 0, 0);
        }
        if (s < 3) {
            u16x4 p0, p1;
            #pragma unroll
            for (int j = 0; j < 4; ++j) {
                p0[j] = f2b(mv[2 * s + 2][j]);
                p1[j] = f2b(mv[2 * s + 3][j]);
            }
            *(u16x4*)&As[(s + 1) & 1][sr0 * AP + sc] = p0;
            *(u16x4*)&As[(s + 1) & 1][sr1 * AP + sc] = p1;
            __syncthreads();                    // only 3 in-loop barriers now
        }
    }

    // ---- deferred out1 copy: stores drain async under epilogue/endpgm
    #pragma unroll
    for (int s = 0; s < 4; ++s) {
        *(f4*)(obase + (size_t)sr0 * SRC + s * 128 + sc) = mv[2 * s];
        *(f4*)(obase + (size_t)sr1 * SRC + s * 128 + sc) = mv[2 * s + 1];
    }

    // epilogue: wave-private 32x32 partial -> BF16 part
    // D layout: col = lane&15 (n), row = quad*4 + reg (m)  [verified m89/m91]
    unsigned short* pb = part + ((size_t)kc * BSZ + b) * TGT * E;
    #pragma unroll
    for (int r = 0; r < 4; ++r) {
        int rr0 = t0 + quad * 4 + r;
        int rr1 = rr0 + 16;
        int c0  = w * 32 + l15;
        pb[(size_t)rr0 * E + c0]      = f2b(acc00[r]);
        pb[(size_t)rr0 * E + c0 + 16] = f2b(acc01[r]);
        pb[(size_t)rr1 * E + c0]      = f2b(acc10[r]);
        pb[(size_t)rr1 * E + c0 + 16] = f2b(acc11[r]);
    }
}

// ---------------------------------------------------------------------------
// gemm2_fused: out0[t,b,:] = (sum_kc part[kc])[b,t,:] @ W^T + bias.
// part BF16 (half the read bytes vs R8; b-slice ~1 MB likely L2-hot).
// ---------------------------------------------------------------------------
#define PSTRIDE ((size_t)BSZ * TGT * E)

__global__ __launch_bounds__(256) void gemm2_fused(
    const unsigned short* __restrict__ part,
    const unsigned short* __restrict__ wf,
    const float* __restrict__ bias,
    float* __restrict__ out0)
{
    __shared__ unsigned short ct[16 * 264];     // 16 t-rows x 256 e, pitch 264
    const int blk  = blockIdx.x;                // 0..127
    const int b    = blk & 7;
    const int tt16 = blk >> 3;                  // 0..15
    const int tid  = threadIdx.x;

    // ---- reduce 8 bf16 K-partials in fp32 -> bf16 LDS tile
    const unsigned short* pb = part + (size_t)b * TGT * E + (size_t)(tt16 * 16) * E;
    #pragma unroll
    for (int i = 0; i < 4; ++i) {
        int idx = i * 256 + tid;                // 0..1023
        int row = idx >> 6;                     // 0..15
        int c4  = idx & 63;
        const unsigned short* ap = pb + (size_t)row * E + c4 * 4;
        f4 s = {};
        #pragma unroll
        for (int p = 0; p < 8; ++p) {
            u16x4 v = *(const u16x4*)(ap + p * PSTRIDE);
            #pragma unroll
            for (int j = 0; j < 4; ++j) s[j] += b2f(v[j]);
        }
        #pragma unroll
        for (int j = 0; j < 4; ++j) ct[row * 264 + c4 * 4 + j] = f2b(s[j]);
    }
    __syncthreads();

    // ---- MFMA: 4 waves x 4 et tiles each
    const int w    = tid >> 6;
    const int lane = tid & 63;
    const int quad = lane >> 4;
    const int l15  = lane & 15;

    bf16x8 A[8];
    #pragma unroll
    for (int ks = 0; ks < 8; ++ks)
        A[ks] = *(const bf16x8*)&ct[l15 * 264 + ks * 32 + quad * 8];

    #pragma unroll
    for (int e4 = 0; e4 < 4; ++e4) {
        int et = w * 4 + e4;
        const unsigned short* bf = wf + ((size_t)et * 8 * 64 + lane) * 8;
        f32x4 acc = {};
        #pragma unroll
        for (int ks = 0; ks < 8; ++ks) {
            bf16x8 bb = *(const bf16x8*)(bf + (size_t)ks * 512);
            acc = __builtin_amdgcn_mfma_f32_16x16x32_bf16(A[ks], bb, acc, 0, 0, 0);
        }
        const float bval = bias[et * 16 + l15];
        #pragma unroll
        for (int r = 0; r < 4; ++r) {
            int t = tt16 * 16 + quad * 4 + r;
            int e = et * 16 + l15;
            out0[(size_t)t * (BSZ * E) + (size_t)b * E + e] = acc[r] + bval;
        }
    }
}

// ---------------------------------------------------------------------------
extern "C" void kernel_launch(void* const* d_in, const int* in_sizes, int n_in,
                              void* d_out, int out_size, void* d_ws, size_t ws_size,
                              hipStream_t stream)
{
    // inputs: 0=query(unused) 1=key(unused) 2=value 3=proposal_mask 4=W 5=bias
    const float* value = (const float*)d_in[2];
    const float* mask  = (const float*)d_in[3];
    const float* wgt   = (const float*)d_in[4];
    const float* bias  = (const float*)d_in[5];

    float* out0 = (float*)d_out;                              // (256,8,256)
    float* out1 = (float*)d_out + (size_t)TGT * BSZ * E;      // (8,256,4096)

    // ws layout: vtf bf16 16.8MB | wf bf16 128KB | part bf16 [8][b][t][e] 8.4MB
    unsigned short* vtf  = (unsigned short*)d_ws;
    unsigned short* wf   = vtf + (size_t)BSZ * E * SRC;
    unsigned short* part = wf + (size_t)16 * 8 * 64 * 8;

    prep<<<dim3(64, 9), 256, 0, stream>>>(value, wgt, vtf, wf);
    gemm1<<<512, 512, 0, stream>>>(mask, vtf, out1, part);
    gemm2_fused<<<128, 256, 0, stream>>>(part, wf, bias, out0);
}